// Round 1
// 1078.902 us; speedup vs baseline: 1.1582x; 1.1582x over previous
//
#include <hip/hip_runtime.h>
#include <math.h>

#define BB 8
#define CC 128
#define NN 2048
#define KK 10
#define TWO_CC 256

// exact-ranking comparator: larger key wins; ties -> smaller index (JAX semantics)
__device__ __forceinline__ void insert10(double (&LV)[10], int (&LI)[10], double v, int m) {
    if (v > LV[9] || (v == LV[9] && m < LI[9])) {
        LV[9] = v; LI[9] = m;
#pragma unroll
        for (int q = 9; q >= 1; --q) {
            bool sw = (LV[q] > LV[q - 1]) || (LV[q] == LV[q - 1] && LI[q] < LI[q - 1]);
            double tv = LV[q], tu = LV[q - 1];
            int iv = LI[q], iu = LI[q - 1];
            LV[q]     = sw ? tu : tv;
            LV[q - 1] = sw ? tv : tu;
            LI[q]     = sw ? iu : iv;
            LI[q - 1] = sw ? iv : iu;
        }
    }
}

// ---------------- squared column norms in f64 ----------------
__global__ __launch_bounds__(256) void k_xx(const float* __restrict__ h, double* __restrict__ xx) {
    int t = blockIdx.x * 256 + threadIdx.x;
    if (t >= BB * NN) return;
    int b = t / NN, n = t % NN;
    const float* p = h + (size_t)b * CC * NN + n;
    double s = 0.0;
#pragma unroll
    for (int c = 0; c < CC; ++c) {
        double v = (double)p[(size_t)c * NN];
        s += v * v;
    }
    xx[t] = s;
}

// ---------------- fused distance + partial top-10 ----------------
// block: 64 rows (n0..n0+63) of batch b, HALF of the candidate range (my*1024 .. +1023).
// 256 threads; tx=t&7 (8 cols each), ty=t>>3 (2 rows each). Per-thread 2x8 f64 tile.
// Writes a sorted partial top-10 per (row, half) to pv/pi; k_kmerge combines halves.
__global__ __launch_bounds__(256, 2) void k_knn(const float* __restrict__ h, const double* __restrict__ xxg,
                                                double* __restrict__ pv, int* __restrict__ pi) {
    __shared__ __align__(16) char smem[65536];
    float* At2 = (float*)smem;                 // [128][64] fp32, k-major
    float* Bsm = (float*)(smem + 32768);       // [128][64] fp32, k-major
    double* mgV = (double*)smem;               // merge overlay on At2: [64][4][10] f64
    int*    mgI = (int*)(smem + 20480);        // [64][4][10] int

    int t = threadIdx.x;
    int tx = t & 7, ty = t >> 3;
    int b = blockIdx.z;
    int my = blockIdx.y;
    int n0 = blockIdx.x * 64;
    const float* hb = h + (size_t)b * CC * NN;

    // stage A-tile transposed: At2[c][j] = h[b][c][n0+j]
#pragma unroll
    for (int i = 0; i < 8; ++i) {
        int G = t + 256 * i;            // 0..2047 float4-groups
        int c = G >> 4, u = G & 15;
        float4 v = *(const float4*)(hb + (size_t)c * NN + n0 + u * 4);
        *(float4*)(At2 + c * 64 + u * 4) = v;
    }

    double LV[2][10]; int LI[2][10];
#pragma unroll
    for (int rr = 0; rr < 2; ++rr)
#pragma unroll
        for (int q = 0; q < 10; ++q) { LV[rr][q] = -1.0e300; LI[rr][q] = 0x7FFFFFFF; }

    for (int mt = 0; mt < 16; ++mt) {
        int m0 = my * 1024 + mt * 64;
        double xxv[8];
#pragma unroll
        for (int j = 0; j < 8; ++j) xxv[j] = xxg[b * NN + m0 + 8 * tx + j];

        __syncthreads();                 // Bsm free (also covers At2 staging on mt=0)
#pragma unroll
        for (int i = 0; i < 8; ++i) {
            int G = t + 256 * i;        // 0..2047 float4-groups
            int c = G >> 4, u = G & 15;
            float4 v = *(const float4*)(hb + (size_t)c * NN + m0 + u * 4);
            *(float4*)(Bsm + c * 64 + u * 4) = v;
        }
        __syncthreads();

        double acc[2][8] = {};
        const float* pA = At2 + 2 * ty;
        const float* pB = Bsm + 8 * tx;
#pragma unroll 4
        for (int k = 0; k < 128; ++k) {
            float2 af = *(const float2*)(pA + k * 64);
            float4 bf0 = *(const float4*)(pB + k * 64);
            float4 bf1 = *(const float4*)(pB + k * 64 + 4);
            double a0 = (double)af.x, a1 = (double)af.y;
            double b0 = (double)bf0.x, b1 = (double)bf0.y, b2 = (double)bf0.z, b3 = (double)bf0.w;
            double b4 = (double)bf1.x, b5 = (double)bf1.y, b6 = (double)bf1.z, b7 = (double)bf1.w;
            acc[0][0] += a0 * b0; acc[0][1] += a0 * b1; acc[0][2] += a0 * b2; acc[0][3] += a0 * b3;
            acc[0][4] += a0 * b4; acc[0][5] += a0 * b5; acc[0][6] += a0 * b6; acc[0][7] += a0 * b7;
            acc[1][0] += a1 * b0; acc[1][1] += a1 * b1; acc[1][2] += a1 * b2; acc[1][3] += a1 * b3;
            acc[1][4] += a1 * b4; acc[1][5] += a1 * b5; acc[1][6] += a1 * b6; acc[1][7] += a1 * b7;
        }
#pragma unroll
        for (int rr = 0; rr < 2; ++rr)
#pragma unroll
            for (int j = 0; j < 8; ++j) {
                double v = 2.0 * acc[rr][j] - xxv[j];
                insert10(LV[rr], LI[rr], v, m0 + 8 * tx + j);
            }
    }

    // hierarchical merge across tx: 8 -> 4 -> 2 -> 1 lists per row
    for (int p = 0; p < 3; ++p) {
        int span = 1 << p;
        __syncthreads();
        bool act = (tx & (span - 1)) == 0;
        int g = tx >> p;
        if (act && (g & 1)) {
            int slot = g >> 1;
#pragma unroll
            for (int rr = 0; rr < 2; ++rr) {
                int base = ((2 * ty + rr) * 4 + slot) * 10;
#pragma unroll
                for (int q = 0; q < 10; ++q) { mgV[base + q] = LV[rr][q]; mgI[base + q] = LI[rr][q]; }
            }
        }
        __syncthreads();
        if (act && !(g & 1)) {
            int slot = g >> 1;
#pragma unroll
            for (int rr = 0; rr < 2; ++rr) {
                int base = ((2 * ty + rr) * 4 + slot) * 10;
#pragma unroll
                for (int q = 0; q < 10; ++q) insert10(LV[rr], LI[rr], mgV[base + q], mgI[base + q]);
            }
        }
    }
    if (tx == 0) {
#pragma unroll
        for (int rr = 0; rr < 2; ++rr) {
            int n = n0 + 2 * ty + rr;
            size_t base = ((size_t)(b * 2 + my) * NN + n) * KK;
#pragma unroll
            for (int q = 0; q < 10; ++q) { pv[base + q] = LV[rr][q]; pi[base + q] = LI[rr][q]; }
        }
    }
}

// ---------------- merge the two m-half partial lists per row ----------------
__global__ __launch_bounds__(256) void k_kmerge(const double* __restrict__ pv, const int* __restrict__ pi,
                                                int* __restrict__ idxout) {
    int r = blockIdx.x * 256 + threadIdx.x;
    if (r >= BB * NN) return;
    int b = r / NN, n = r % NN;
    size_t base0 = ((size_t)(b * 2 + 0) * NN + n) * KK;
    size_t base1 = ((size_t)(b * 2 + 1) * NN + n) * KK;
    double LV[10]; int LI[10];
#pragma unroll
    for (int q = 0; q < 10; ++q) { LV[q] = pv[base0 + q]; LI[q] = pi[base0 + q]; }
#pragma unroll
    for (int q = 0; q < 10; ++q) insert10(LV, LI, pv[base1 + q], pi[base1 + q]);
    int* op = idxout + (size_t)r * KK;
#pragma unroll
    for (int q = 0; q < 10; ++q) op[q] = LI[q];
}

// ---------------- transpose: ht[b][n][c] = h[b][c][n] ----------------
__global__ __launch_bounds__(256) void k_tr(const float* __restrict__ h, float* __restrict__ ht) {
    __shared__ float tile[32][33];
    int b = blockIdx.z, c0 = blockIdx.y * 32, n0 = blockIdx.x * 32;
    int tx = threadIdx.x & 31, tyy = threadIdx.x >> 5;
    const float* hb = h + (size_t)b * CC * NN;
#pragma unroll
    for (int i = 0; i < 4; ++i)
        tile[tyy + i * 8][tx] = hb[(size_t)(c0 + tyy + i * 8) * NN + n0 + tx];
    __syncthreads();
    float* htb = ht + (size_t)b * NN * CC;
#pragma unroll
    for (int i = 0; i < 4; ++i)
        htb[(size_t)(n0 + tyy + i * 8) * CC + c0 + tx] = tile[tx][tyy + i * 8];
}

// ---------------- coalesced neighbor mean from ht ----------------
__global__ __launch_bounds__(256) void k_gather(const float* __restrict__ ht, const int* __restrict__ idx,
                                                float* __restrict__ M) {
    int bn = blockIdx.x * 2 + (threadIdx.x >> 7);
    int c = threadIdx.x & 127;
    int b = bn >> 11;
    const int* ip = idx + (size_t)bn * KK;
    const float* hb = ht + (size_t)b * NN * CC;
    float s = 0.f;
#pragma unroll
    for (int k = 0; k < KK; ++k) s += hb[(size_t)ip[k] * CC + c];
    M[(size_t)bn * CC + c] = s * (1.f / KK);
}

// ---------------- y = Wa*M + (Wb-Wa)*h + bias ----------------
__global__ __launch_bounds__(256) void k_gemm(const float* __restrict__ M, const float* __restrict__ h,
                                              const float* __restrict__ W, const float* __restrict__ bias,
                                              float* __restrict__ y) {
    __shared__ float Ws[64][33];
    __shared__ float Xs[32][65];
    int b = blockIdx.z;
    int o0 = blockIdx.y * 64;
    int n0 = blockIdx.x * 64;
    int tid = threadIdx.x;
    int tx = tid & 15, ty = tid >> 4;
    float acc[4][4] = {};
    const float* Mb = M + (size_t)b * NN * CC;
    const float* hb = h + (size_t)b * CC * NN;

    for (int c0 = 0; c0 < CC; c0 += 32) {
        for (int i = tid; i < 64 * 32; i += 256) {
            int c = i & 31, o = i >> 5;
            Ws[o][c] = W[(size_t)(o0 + o) * TWO_CC + c0 + c];
        }
        for (int i = tid; i < 64 * 32; i += 256) {
            int c = i & 31, nn = i >> 5;
            Xs[c][nn] = Mb[(size_t)(n0 + nn) * CC + c0 + c];
        }
        __syncthreads();
        for (int c = 0; c < 32; ++c) {
            float a[4], bb[4];
#pragma unroll
            for (int q = 0; q < 4; ++q) { a[q] = Ws[ty * 4 + q][c]; bb[q] = Xs[c][tx * 4 + q]; }
#pragma unroll
            for (int i2 = 0; i2 < 4; ++i2)
#pragma unroll
                for (int j = 0; j < 4; ++j) acc[i2][j] += a[i2] * bb[j];
        }
        __syncthreads();
    }
    for (int c0 = 0; c0 < CC; c0 += 32) {
        for (int i = tid; i < 64 * 32; i += 256) {
            int c = i & 31, o = i >> 5;
            const float* wr = W + (size_t)(o0 + o) * TWO_CC;
            Ws[o][c] = wr[CC + c0 + c] - wr[c0 + c];
        }
        for (int i = tid; i < 64 * 32; i += 256) {
            int nn = i & 63, c = i >> 6;
            Xs[c][nn] = hb[(size_t)(c0 + c) * NN + n0 + nn];
        }
        __syncthreads();
        for (int c = 0; c < 32; ++c) {
            float a[4], bb[4];
#pragma unroll
            for (int q = 0; q < 4; ++q) { a[q] = Ws[ty * 4 + q][c]; bb[q] = Xs[c][tx * 4 + q]; }
#pragma unroll
            for (int i2 = 0; i2 < 4; ++i2)
#pragma unroll
                for (int j = 0; j < 4; ++j) acc[i2][j] += a[i2] * bb[j];
        }
        __syncthreads();
    }
#pragma unroll
    for (int i2 = 0; i2 < 4; ++i2) {
        int o = o0 + ty * 4 + i2;
        float bv = bias[o];
#pragma unroll
        for (int j = 0; j < 4; ++j)
            y[((size_t)b * CC + o) * NN + n0 + tx * 4 + j] = acc[i2][j] + bv;
    }
}

// ---------------- per-(b,o) mean/var(ddof=1), relu, optional residual ----------------
__global__ __launch_bounds__(256) void k_norm(const float* __restrict__ y, const float* __restrict__ res,
                                              float* __restrict__ out, int add_res) {
    int bo = blockIdx.x;
    const float* row = y + (size_t)bo * NN;
    float s = 0.f, s2 = 0.f;
    for (int n = threadIdx.x; n < NN; n += 256) {
        float v = row[n];
        s += v;
        s2 += v * v;
    }
#pragma unroll
    for (int off = 32; off > 0; off >>= 1) {
        s += __shfl_down(s, off, 64);
        s2 += __shfl_down(s2, off, 64);
    }
    __shared__ float ss[4], ss2[4];
    int wave = threadIdx.x >> 6, lane = threadIdx.x & 63;
    if (lane == 0) { ss[wave] = s; ss2[wave] = s2; }
    __syncthreads();
    if (threadIdx.x == 0) {
        float S = ss[0] + ss[1] + ss[2] + ss[3];
        float S2 = ss2[0] + ss2[1] + ss2[2] + ss2[3];
        float mean = S * (1.f / NN);
        float var = (S2 - S * mean) * (1.f / (NN - 1));
        ss[0] = mean;
        ss2[0] = rsqrtf(var + 1e-3f);
    }
    __syncthreads();
    float mean = ss[0], inv = ss2[0];
    for (int n = threadIdx.x; n < NN; n += 256) {
        float v = (row[n] - mean) * inv;
        v = fmaxf(v, 0.f);
        if (add_res) v += res[(size_t)bo * NN + n];
        out[(size_t)bo * NN + n] = v;
    }
}

extern "C" void kernel_launch(void* const* d_in, const int* in_sizes, int n_in,
                              void* d_out, int out_size, void* d_ws, size_t ws_size,
                              hipStream_t stream) {
    const float* x  = (const float*)d_in[0];
    const float* W1 = (const float*)d_in[1];
    const float* b1 = (const float*)d_in[2];
    const float* W2 = (const float*)d_in[3];
    const float* b2 = (const float*)d_in[4];
    float* out = (float*)d_out;

    char* wsb = (char*)d_ws;
    double* xx = (double*)wsb;                          // 8*2048 f64          = 131072 B
    char* p = wsb + (size_t)BB * NN * 8;
    int* idx = (int*)p;       p += (size_t)BB * NN * KK * 4;    // 655360 B
    float* ht = (float*)p;    p += (size_t)BB * NN * CC * 4;    // 8 MB
    float* M  = (float*)p;    p += (size_t)BB * NN * CC * 4;    // 8 MB
    float* y  = (float*)p;    p += (size_t)BB * CC * NN * 4;    // 8 MB
    float* h1 = (float*)p;                                      // 8 MB

    // partial top-10 lists (per m-half) live in y's region — y is dead during the KNN phase.
    double* pv = (double*)y;                                    // 8*2*2048*10*8 = 2.62 MB
    int*    pi = (int*)((char*)y + (size_t)BB * 2 * NN * KK * 8);   // +1.31 MB  (< 8 MB total)

    auto layer = [&](const float* hin, const float* Wt, const float* bt, float* hout, int add_res) {
        hipLaunchKernelGGL(k_xx, dim3((BB * NN) / 256), dim3(256), 0, stream, hin, xx);
        hipLaunchKernelGGL(k_tr, dim3(NN / 32, CC / 32, BB), dim3(256), 0, stream, hin, ht);
        hipLaunchKernelGGL(k_knn, dim3(NN / 64, 2, BB), dim3(256), 0, stream, hin, xx, pv, pi);
        hipLaunchKernelGGL(k_kmerge, dim3((BB * NN) / 256), dim3(256), 0, stream, pv, pi, idx);
        hipLaunchKernelGGL(k_gather, dim3(BB * NN / 2), dim3(256), 0, stream, ht, idx, M);
        hipLaunchKernelGGL(k_gemm, dim3(NN / 64, CC / 64, BB), dim3(256), 0, stream, M, hin, Wt, bt, y);
        hipLaunchKernelGGL(k_norm, dim3(BB * CC), dim3(256), 0, stream, y, x, hout, add_res);
    };

    layer(x, W1, b1, h1, 0);
    layer(h1, W2, b2, out, 1);
}